// Round 7
// baseline (264.462 us; speedup 1.0000x reference)
//
#include <hip/hip_runtime.h>

#define NFFT 3072
#define THREADS 256
#define HOP 192
#define HALF 1536
#define TFRAMES 1000
#define OUTLEN 191808
#define NBANDS 128
#define PI_F 3.14159265358979323846f
#define NPAIR 4                   // frame-pairs per block (8 frames)
#define NSB 125                   // supersegments per batch: 1000/8

__device__ __forceinline__ float2 cadd(float2 a,float2 b){return make_float2(a.x+b.x,a.y+b.y);}
__device__ __forceinline__ float2 csub(float2 a,float2 b){return make_float2(a.x-b.x,a.y-b.y);}
__device__ __forceinline__ float2 cmul(float2 a,float2 b){
    return make_float2(fmaf(a.x,b.x,-a.y*b.y), fmaf(a.x,b.y,a.y*b.x));
}
__device__ __forceinline__ float2 cmuln_i(float2 a){return make_float2(a.y,-a.x);}  // a * (-i)
__device__ __forceinline__ float2 cneg(float2 a){return make_float2(-a.x,-a.y);}

// LDS padding: +1 float2 every 16 (128B) to break mod-16 bank aliasing
__device__ __forceinline__ int IDX(int i){ return i + (i>>4); }

__device__ __forceinline__ void dft4(float2 a0,float2 a1,float2 a2,float2 a3,
                                     float2&y0,float2&y1,float2&y2,float2&y3){
    float2 e0=cadd(a0,a2), e1=csub(a0,a2), o0=cadd(a1,a3), o1=csub(a1,a3);
    y0=cadd(e0,o0); y2=csub(e0,o0);
    float2 io=make_float2(-o1.y,o1.x);   // i*o1
    y1=csub(e1,io); y3=cadd(e1,io);
}
__device__ __forceinline__ void dft3(float2 a0,float2 a1,float2 a2,
                                     float2&y0,float2&y1,float2&y2){
    float2 s=cadd(a1,a2), d=csub(a1,a2);
    y0=cadd(a0,s);
    float2 t=make_float2(a0.x-0.5f*s.x, a0.y-0.5f*s.y);
    const float S3=0.86602540378443864676f;
    float2 id=make_float2(S3*d.y,-S3*d.x);   // -i*S3*d
    y1=cadd(t,id); y2=csub(t,id);
}

// 12-point DFT: o[j] = sum_l a[l] w12^{lj}.  12 = 4x3
__device__ __forceinline__ void dft12(float2 a[12], float2 o[12]){
    float2 u[3][4];
    #pragma unroll
    for(int n2=0;n2<3;++n2)
        dft4(a[n2],a[3+n2],a[6+n2],a[9+n2],u[n2][0],u[n2][1],u[n2][2],u[n2][3]);
    const float2 W1=make_float2( 0.86602540378443865f,-0.5f);
    const float2 W2=make_float2( 0.5f,-0.86602540378443865f);
    const float2 W4=make_float2(-0.5f,-0.86602540378443865f);
    u[1][1]=cmul(u[1][1],W1); u[1][2]=cmul(u[1][2],W2); u[1][3]=cmuln_i(u[1][3]);
    u[2][1]=cmul(u[2][1],W2); u[2][2]=cmul(u[2][2],W4); u[2][3]=cneg(u[2][3]);
    #pragma unroll
    for(int k1=0;k1<4;++k1)
        dft3(u[0][k1],u[1][k1],u[2][k1], o[k1],o[k1+4],o[k1+8]);
}

// 16-point DFT: 16 = 4x4
__device__ __forceinline__ void dft16(float2 a[16], float2 o[16]){
    float2 u[4][4];
    #pragma unroll
    for(int n2=0;n2<4;++n2)
        dft4(a[n2],a[4+n2],a[8+n2],a[12+n2],u[n2][0],u[n2][1],u[n2][2],u[n2][3]);
    const float C16=0.92387953251128674f, S16=0.38268343236508977f, R2=0.70710678118654752f;
    const float2 W1=make_float2( C16,-S16), W2=make_float2( R2,-R2), W3=make_float2( S16,-C16);
    const float2 W6=make_float2(-R2,-R2),  W9=make_float2(-C16, S16);
    u[1][1]=cmul(u[1][1],W1); u[1][2]=cmul(u[1][2],W2);   u[1][3]=cmul(u[1][3],W3);
    u[2][1]=cmul(u[2][1],W2); u[2][2]=cmuln_i(u[2][2]);   u[2][3]=cmul(u[2][3],W6);
    u[3][1]=cmul(u[3][1],W3); u[3][2]=cmul(u[3][2],W6);   u[3][3]=cmul(u[3][3],W9);
    #pragma unroll
    for(int k1=0;k1<4;++k1)
        dft4(u[0][k1],u[1][k1],u[2][k1],u[3][k1], o[k1],o[k1+4],o[k1+8],o[k1+12]);
}

// multiply o[j] *= w^j, w = e^{i*ang};  power tree
template<int R>
__device__ __forceinline__ void twiddle_pows(float2* o, float ang){
    float s,c; __sincosf(ang,&s,&c);
    float2 w1=make_float2(c,s);
    float2 w2=cmul(w1,w1);
    float2 w3=cmul(w2,w1);
    float2 w4=cmul(w2,w2);
    o[1]=cmul(o[1],w1); o[2]=cmul(o[2],w2); o[3]=cmul(o[3],w3);
    float2 w8=cmul(w4,w4);
    float2 w5=cmul(w4,w1), w6=cmul(w4,w2), w7=cmul(w4,w3);
    o[4]=cmul(o[4],w4); o[5]=cmul(o[5],w5); o[6]=cmul(o[6],w6); o[7]=cmul(o[7],w7);
    float2 w9=cmul(w8,w1), w10=cmul(w8,w2), w11=cmul(w8,w3);
    o[8]=cmul(o[8],w8); o[9]=cmul(o[9],w9); o[10]=cmul(o[10],w10); o[11]=cmul(o[11],w11);
    if constexpr (R>12){
        float2 w12=cmul(w8,w4), w13=cmul(w8,w5), w14=cmul(w8,w6), w15=cmul(w8,w7);
        o[12]=cmul(o[12],w12); o[13]=cmul(o[13],w13); o[14]=cmul(o[14],w14); o[15]=cmul(o[15],w15);
    }
}

// Stockham stage B: (NN=256, S=12, R=16)
__device__ __forceinline__ void stageB(float2* A, int tid){
    const bool act = tid < 192;
    float2 o[16];
    int q=0,p=0;
    if(act){
        q = tid % 12; p = tid / 12;
        float2 a[16];
        int ib = IDX(q + 12*p);            // linear stride 192 -> padded 204
        #pragma unroll
        for(int l=0;l<16;++l) a[l] = A[ib + 204*l];
        dft16(a,o);
        twiddle_pows<16>(o, -2.0f*PI_F*(float)p*(1.0f/256.0f));
    }
    __syncthreads();
    if(act){
        #pragma unroll
        for(int j=0;j<16;++j) A[IDX(q + 192*p + 12*j)] = o[j];
    }
    __syncthreads();
}

// One block: 4 frame-pairs (8 frames) -> 4x (FFT, filter, IFFT, window),
// overlap-added into a rolling 17-register window (all indices static),
// streamed to global with ~1/14 the atomics of the per-pair version.
__global__ __launch_bounds__(THREADS,4)
void filtered_noise_kernel(const float* __restrict__ fb,
                           const float* __restrict__ noise,
                           float* __restrict__ out)
{
    __shared__ float2 A[NFFT + NFFT/16];   // 3264 float2 = 26112 B
    __shared__ float gfs[NBANDS*2*NPAIR];  // [band][frame 0..7] = 4 KB

    const int tid = threadIdx.x;
    // XCD swizzle: grid 1000 = 8 x 125; blockIdx%8 -> XCD round robin.
    const int b   = blockIdx.x & 7;
    const int sb  = blockIdx.x >> 3;       // supersegment 0..124
    const int T0  = sb * (2*NPAIR);        // first frame of this block
    const float* nz = noise + (size_t)b * OUTLEN;
    const int blockbase = T0*HOP - HALF;   // out index of combined sample 0

    // filter gains for all 8 frames: gfs[f*8 + ft] = fb[b][f][T0+ft]
    #pragma unroll
    for(int i=0;i<4;++i){
        int idx = tid + 256*i;             // 0..1023
        int f = idx >> 3, ft = idx & 7;
        gfs[idx] = fb[((size_t)b*NBANDS + f)*TFRAMES + T0 + ft];
    }

    // Hann*1/N window samples this thread touches (same for every pair)
    const bool act = tid < 192;
    float hw[16];
    {
        const float invN = 1.0f/(float)NFFT;
        #pragma unroll
        for(int j=0;j<16;++j){
            int n = tid + 192*j;
            hw[j] = invN*(0.5f - 0.5f*__cosf(2.0f*PI_F*(float)n*(1.0f/3071.0f)));
        }
    }

    // rolling OLA window: acc[d] = combined index m = 2*pi + d, d in [0,17)
    float acc[17];
    #pragma unroll
    for(int d=0;d<17;++d) acc[d]=0.0f;

    float* outb = out + (size_t)b * OUTLEN;

    for(int pi=0; pi<NPAIR; ++pi){
        const int t0 = T0 + 2*pi;
        const int base0 = t0*HOP - HALF;
        const int tt = 2*pi;

        __syncthreads();                   // prev pair's phase-6 reads done

        // ---- Phase 1: fwd stage A (R=12), global -> LDS ----
        {
            float2 a[12], o[12];
            #pragma unroll
            for(int l=0;l<12;++l){
                int i0 = base0 + tid + 256*l;
                float x0 = (i0 >= 0 && i0 < OUTLEN) ? nz[i0] : 0.0f;
                int i1 = i0 + HOP;
                float x1 = (i1 >= 0 && i1 < OUTLEN) ? nz[i1] : 0.0f;
                a[l] = make_float2(x0, x1);
            }
            dft12(a,o);
            twiddle_pows<12>(o, -2.0f*PI_F*(float)tid*(1.0f/3072.0f));
            #pragma unroll
            for(int j=0;j<12;++j) A[IDX(12*tid + j)] = o[j];
        }
        __syncthreads();

        // ---- Phase 2: fwd stage B ----
        stageB(A, tid);

        // ---- Phase 3: fwd stage C (R=16, no twiddle), in-place ----
        {
            float2 o[16];
            if(act){
                float2 a[16];
                int ib = IDX(tid);
                #pragma unroll
                for(int l=0;l<16;++l) a[l] = A[ib + 204*l];
                dft16(a,o);
            }
            __syncthreads();
            if(act){
                int ib = IDX(tid);
                #pragma unroll
                for(int j=0;j<16;++j) A[ib + 204*j] = o[j];
            }
            __syncthreads();
        }

        // ---- Phase 4: spectral multiply fused into inv stage A (R=12) ----
        // Z[k] at A[IDX(k)]; linear stride 256 -> padded 272.
        // W'[k] = a_k*conj(Z[k]) + b_k*Z[N-k]
        {
            const int p = tid;
            float2 z[12], zm[12];
            {
                int ib = IDX(p);
                #pragma unroll
                for(int l=0;l<12;++l) z[l] = A[ib + 272*l];     // Z[p + 256*l]
            }
            {
                int pm = (p==0) ? 0 : (256 - p);
                int ib = IDX(pm);
                #pragma unroll
                for(int l=0;l<12;++l) zm[l] = A[ib + 272*l];    // Z[pm + 256*l]
            }
            float2 w[12];
            #pragma unroll
            for(int l=0;l<12;++l){
                int k = p + 256*l;
                int j = (k <= HALF) ? k : (NFFT - k);
                float aa = 0.0f, bb = 0.0f;
                if(j){
                    int band = (j-1)/12;
                    float Gx = gfs[(band<<3) + tt];
                    float Gy = gfs[(band<<3) + tt + 1];
                    aa = 0.5f*(Gx+Gy); bb = 0.5f*(Gx-Gy);
                }
                float2 Zm = (p==0) ? ((l==0) ? z[0] : z[12-l]) : zm[11-l];
                w[l] = make_float2( fmaf(aa, z[l].x,  bb*Zm.x),
                                    fmaf(-aa, z[l].y, bb*Zm.y) );
            }
            float2 o[12];
            dft12(w,o);
            twiddle_pows<12>(o, -2.0f*PI_F*(float)p*(1.0f/3072.0f));
            __syncthreads();                    // all reads done before writes
            #pragma unroll
            for(int j=0;j<12;++j) A[IDX(12*p + j)] = o[j];
            __syncthreads();
        }

        // ---- Phase 5: inv stage B ----
        stageB(A, tid);

        // ---- Phase 6: inv stage C + window -> rolling register OLA ----
        // pair-local c = tid+192j gets o[j].x (frame t0) and o[j-1].y (frame
        // t0+1, shifted by HOP); block-combined m = j + 2*pi.
        if(act){
            float2 a[16], o[16];
            int ib = IDX(tid);
            #pragma unroll
            for(int l=0;l<16;++l) a[l] = A[ib + 204*l];
            dft16(a,o);
            #pragma unroll
            for(int j=0;j<16;++j){
                float s = hw[j];
                acc[j]   = fmaf( o[j].x, s, acc[j]);
                acc[j+1] = fmaf(-o[j].y, s, acc[j+1]);
            }
            // acc[0], acc[1] (m = 2pi, 2pi+1) are final: stream them out
            int p0 = blockbase + tid + 192*tt;
            if (p0 >= 0 && p0 < OUTLEN) atomicAdd(&outb[p0], acc[0]);
            int p1 = p0 + HOP;
            if (p1 >= 0 && p1 < OUTLEN) atomicAdd(&outb[p1], acc[1]);
        }
        // shift window down by 2
        #pragma unroll
        for(int d=0;d<15;++d) acc[d] = acc[d+2];
        acc[15]=0.0f; acc[16]=0.0f;
    }

    // epilogue: remaining m = 8..22 (acc[0..14] after the last shift)
    if(act){
        #pragma unroll
        for(int d=0;d<15;++d){
            int p = blockbase + tid + 192*(2*NPAIR + d);
            if (p >= 0 && p < OUTLEN) atomicAdd(&outb[p], acc[d]);
        }
    }
}

extern "C" void kernel_launch(void* const* d_in, const int* in_sizes, int n_in,
                              void* d_out, int out_size, void* d_ws, size_t ws_size,
                              hipStream_t stream)
{
    const float* fb    = (const float*)d_in[0];   // (8,1,128,1000) f32
    const float* noise = (const float*)d_in[1];   // (8,1,191808)   f32
    float* out = (float*)d_out;                   // (8,1,191808)   f32

    const int B = in_sizes[1] / OUTLEN;           // 8

    hipMemsetAsync(out, 0, (size_t)out_size * sizeof(float), stream);

    dim3 grid(B * NSB);                           // 1000 blocks, 8 frames each
    filtered_noise_kernel<<<grid, THREADS, 0, stream>>>(fb, noise, out);
}